// Round 9
// baseline (303.230 us; speedup 1.0000x reference)
//
#include <hip/hip_runtime.h>

#define F16 _Float16
typedef _Float16 f16x8 __attribute__((ext_vector_type(8)));
typedef _Float16 f16x4 __attribute__((ext_vector_type(4)));
typedef float f32x4 __attribute__((ext_vector_type(4)));

#define NB    4
#define CIN   512
#define NN    4096
#define KCH   256
#define OCH   512
#define BNEPS 1e-5f
#define PSET  ((size_t)NB * NN * KCH)        // elements per partial set
#define NBNN  (NB * NN)

// async global->LDS, 16B per lane (dest = uniform base + lane*16)
__device__ __forceinline__ void gl16(const F16* g, F16* l) {
    __builtin_amdgcn_global_load_lds((const __attribute__((address_space(1))) void*)g,
                                     (__attribute__((address_space(3))) void*)l, 16, 0, 0);
}

// ---------------------------------------------------------------- transpose
__global__ __launch_bounds__(256) void k_transpose(const float* __restrict__ x,
                                                   F16* __restrict__ xT) {
    __shared__ float tile[64][65];
    int b = blockIdx.z, n0 = blockIdx.y * 64, c0 = blockIdx.x * 64;
    int t = threadIdx.x;
    const float* xb = x + (size_t)b * CIN * NN;
#pragma unroll
    for (int i = 0; i < 4; i++) {
        int c = (t >> 4) + i * 16;
        int n = (t & 15) * 4;
        float4 v = *(const float4*)&xb[(size_t)(c0 + c) * NN + n0 + n];
        tile[c][n + 0] = v.x; tile[c][n + 1] = v.y;
        tile[c][n + 2] = v.z; tile[c][n + 3] = v.w;
    }
    __syncthreads();
    F16* xTb = xT + (size_t)b * NN * CIN;
#pragma unroll
    for (int i = 0; i < 4; i++) {
        int n = (t >> 4) + i * 16;
        int c = (t & 15) * 4;
        f16x4 o;
        o[0] = (F16)tile[c + 0][n]; o[1] = (F16)tile[c + 1][n];
        o[2] = (F16)tile[c + 2][n]; o[3] = (F16)tile[c + 3][n];
        *(f16x4*)&xTb[(size_t)(n0 + n) * CIN + c0 + c] = o;
    }
}

// ---------------------------------------------------------------- K/V GEMM
__global__ __launch_bounds__(256) void k_kv_gemm(
    const F16* __restrict__ xT,
    const float* __restrict__ key_w, const float* __restrict__ key_b,
    const float* __restrict__ gamma, const float* __restrict__ beta,
    const float* __restrict__ mean,  const float* __restrict__ var,
    const float* __restrict__ value_w, const float* __restrict__ value_b,
    F16* __restrict__ KQt, F16* __restrict__ Vg) {
    __shared__ F16 Al[128][40];
    __shared__ F16 Bl[128][40];
    int b = blockIdx.z;
    int m0 = blockIdx.y * 128;
    int n0 = blockIdx.x * 128;
    int t = threadIdx.x, w = t >> 6, l = t & 63;
    int wr = w >> 1, wc = w & 1;
    int lr = l >> 4, lc = l & 15;
    f32x4 acc[4][4];
    const f32x4 fz = {0.f, 0.f, 0.f, 0.f};
#pragma unroll
    for (int i = 0; i < 4; i++)
#pragma unroll
        for (int j = 0; j < 4; j++) acc[i][j] = fz;
    const F16* xb = xT + (size_t)b * NN * CIN;

    for (int kt = 0; kt < CIN / 32; kt++) {
        int c0 = kt * 32;
        __syncthreads();
#pragma unroll
        for (int p = 0; p < 4; p++) {
            int row = (t >> 3) + p * 32;
            int cc = (t & 7) * 4;
            int rg = m0 + row;
            const float* src = (rg < 256) ? (key_w + (size_t)rg * CIN)
                                          : (value_w + (size_t)(rg - 256) * CIN);
            float4 v = *(const float4*)&src[c0 + cc];
            f16x4 h; h[0] = (F16)v.x; h[1] = (F16)v.y; h[2] = (F16)v.z; h[3] = (F16)v.w;
            *(f16x4*)&Al[row][cc] = h;
        }
#pragma unroll
        for (int p = 0; p < 2; p++) {
            int row = (t >> 2) + p * 64;
            int cc = (t & 3) * 8;
            *(int4*)&Bl[row][cc] = *(const int4*)&xb[(size_t)(n0 + row) * CIN + c0 + cc];
        }
        __syncthreads();
        f16x8 a[4];
#pragma unroll
        for (int fi = 0; fi < 4; fi++)
            a[fi] = *(f16x8*)&Al[wr * 64 + fi * 16 + lc][lr * 8];
#pragma unroll
        for (int fj = 0; fj < 4; fj++) {
            f16x8 bb = *(f16x8*)&Bl[wc * 64 + fj * 16 + lc][lr * 8];
#pragma unroll
            for (int fi = 0; fi < 4; fi++)
                acc[fi][fj] = __builtin_amdgcn_mfma_f32_16x16x32_f16(a[fi], bb, acc[fi][fj], 0, 0, 0);
        }
    }

    if (m0 < 256) {
#pragma unroll
        for (int fi = 0; fi < 4; fi++) {
            int ch0 = m0 + wr * 64 + fi * 16 + lr * 4;
            float invs[4], mns[4], bts[4], kbs[4];
#pragma unroll
            for (int r = 0; r < 4; r++) {
                int ch = ch0 + r;
                invs[r] = gamma[ch] * rsqrtf(var[ch] + BNEPS);
                mns[r] = mean[ch]; bts[r] = beta[ch]; kbs[r] = key_b[ch];
            }
#pragma unroll
            for (int fj = 0; fj < 4; fj++) {
                int n = n0 + wc * 64 + fj * 16 + lc;
                f16x4 o;
#pragma unroll
                for (int r = 0; r < 4; r++) {
                    float v = (acc[fi][fj][r] + kbs[r] - mns[r]) * invs[r] + bts[r];
                    v = fmaxf(v, 0.0f);
                    o[r] = (F16)v;
                }
                *(f16x4*)&KQt[((size_t)b * NN + n) * KCH + ch0] = o;
            }
        }
    } else {
#pragma unroll
        for (int fi = 0; fi < 4; fi++) {
            int v0 = m0 - 256 + wr * 64 + fi * 16 + lr * 4;
#pragma unroll
            for (int fj = 0; fj < 4; fj++) {
                int n = n0 + wc * 64 + fj * 16 + lc;
#pragma unroll
                for (int r = 0; r < 4; r++) {
                    float vv = acc[fi][fj][r] + value_b[v0 + r];
                    Vg[((size_t)b * KCH + v0 + r) * NN + n] = (F16)vv;
                }
            }
        }
    }
}

// ---------------------------------------------------------------- flash attention
// KVBLK=32, split-K S=4 -> 1024 blocks = 4 blocks/CU (LDS 37 KB, 16 waves/CU).
// 2 key-streams per XCD (kset=(xcd&1)*2+(hi&1)). Q in regs; global_load_lds
// staging (K pre-swizzled source, V linear); PV split by v-slice; l via MFMA.
__global__ __launch_bounds__(256, 4) void k_flash(const F16* __restrict__ KQt,
                                                  const F16* __restrict__ Vg,
                                                  F16* __restrict__ parts,
                                                  float* __restrict__ Lbuf) {
    __shared__ __align__(16) F16 Kl[32 * 256];    // 16 KB, row stride 512B
    __shared__ __align__(16) F16 Vl[256 * 32];    // 16 KB, row stride 64B
    __shared__ __align__(16) F16 Ps[64 * 32];     //  4 KB, row stride 64B
    __shared__ __align__(16) float crl[64];
    __shared__ int rflag[2];
    int bid = blockIdx.x;
    int xcd = bid & 7;
    int b = xcd >> 1;                          // batch pinned to an XCD pair
    int hi = bid >> 3;                         // 0..127
    int kset = (xcd & 1) * 2 + (hi & 1);       // 2 streams per XCD
    int qtile = hi >> 1;                       // 0..63
    int n0 = qtile * 64;
    int kbase = kset * 1024;
    int t = threadIdx.x, w = t >> 6, l = t & 63;
    int lr = l >> 4, lc = l & 15;
    int kx = lc & 7;                           // K read XOR (row&7 congruent)
    int pswz = (lc >> 2) & 3;                  // P read XOR ((row>>2)&3 congruent)
    int vs = w * 64;                           // wave's v-slice for PV
    const F16* kqb = KQt + (size_t)b * NN * KCH;
    const F16* vgb = Vg + (size_t)b * KCH * NN;
    const float scale = 0.0625f;

    if (t == 0) { rflag[0] = 0; rflag[1] = 0; }

    // Q tile -> registers (A-frag: row = w*16+lc, c-cols = cs*32 + lr*8)
    f16x8 qreg[8];
    {
        const F16* qrow = kqb + (size_t)(n0 + w * 16 + lc) * KCH + lr * 8;
#pragma unroll
        for (int cs = 0; cs < 8; cs++)
            qreg[cs] = *(const f16x8*)&qrow[cs * 32];
    }
    f16x8 one8;
#pragma unroll
    for (int j = 0; j < 8; j++) one8[j] = (F16)1.0f;

    f32x4 acc[4][4];                           // [qf][fv]: 64 q-rows x 64 v-slice
    const f32x4 fz = {0.f, 0.f, 0.f, 0.f};
#pragma unroll
    for (int i = 0; i < 4; i++)
#pragma unroll
        for (int j = 0; j < 4; j++) acc[i][j] = fz;
    f32x4 lsum = fz;                           // own q-rows softmax denominator
    float m_run[4] = {-1e30f, -1e30f, -1e30f, -1e30f};

    // staging lane constants
    int khalf = l >> 5;                        // K: row within pair
    int kc = l & 31;                           // K chunk slot (16B)
    int vloc = l >> 2;                         // V: row within 16-row group
    int vc = l & 3;                            // V chunk slot

    for (int mt = 0; mt < 32; mt++) {
        int m0 = kbase + mt * 32;
        __syncthreads();                       // all waves done with Kl/Vl/Ps
        // stage K rows [w*8, w*8+8): 4 calls x (2 rows x 32 chunks)
#pragma unroll
        for (int p = 0; p < 4; p++) {
            int row = w * 8 + 2 * p + khalf;
            int srcc = kc ^ (row & 7);
            gl16(kqb + (size_t)(m0 + row) * KCH + srcc * 8,
                 &Kl[(w * 8 + 2 * p) * 256]);
        }
        // stage V rows [w*64, w*64+64): 4 calls x (16 rows x 4 chunks), linear
#pragma unroll
        for (int p = 0; p < 4; p++) {
            int row = w * 64 + p * 16 + vloc;
            gl16(vgb + (size_t)row * NN + m0 + vc * 8,
                 &Vl[(w * 64 + p * 16) * 32]);
        }
        __syncthreads();                       // drain -> tiles visible

        // S = Q K^T (wave: 16 q-rows x 32 k-cols, contraction 256)
        f32x4 s[2];
        s[0] = fz; s[1] = fz;
#pragma unroll
        for (int cs = 0; cs < 8; cs++) {
#pragma unroll
            for (int f = 0; f < 2; f++) {
                f16x8 bb = *(f16x8*)&Kl[(f * 16 + lc) * 256 + (((cs * 4 + lr) ^ kx) << 3)];
                s[f] = __builtin_amdgcn_mfma_f32_16x16x32_f16(qreg[cs], bb, s[f], 0, 0, 0);
            }
        }

        // defer-max online softmax: lane-local guard, rare wave-reduce path
        float lm[4], cr[4];
#pragma unroll
        for (int r = 0; r < 4; r++) {
            lm[r] = fmaxf(s[0][r], s[1][r]) * scale;
            cr[r] = 1.0f;
        }
        int ok = (lm[0] <= m_run[0] + 8.0f) && (lm[1] <= m_run[1] + 8.0f) &&
                 (lm[2] <= m_run[2] + 8.0f) && (lm[3] <= m_run[3] + 8.0f);
        if (!__all(ok)) {
#pragma unroll
            for (int r = 0; r < 4; r++) {
                float mx = lm[r];
#pragma unroll
                for (int off = 1; off < 16; off <<= 1)
                    mx = fmaxf(mx, __shfl_xor(mx, off, 64));
                float mnew = fmaxf(m_run[r], mx);
                cr[r] = __expf(m_run[r] - mnew);
                m_run[r] = mnew;
                lsum[r] *= cr[r];
            }
            if (l == 0) rflag[mt & 1] = 1;
        }
        if (lc == 0) {
#pragma unroll
            for (int r = 0; r < 4; r++) crl[w * 16 + lr * 4 + r] = cr[r];
        }
        // P = exp(s*scale - m_run) -> Ps, chunk XOR by (prow>>2)&3 = lr
#pragma unroll
        for (int r = 0; r < 4; r++) {
            int prow = w * 16 + lr * 4 + r;
#pragma unroll
            for (int f = 0; f < 2; f++) {
                float p = __expf(s[f][r] * scale - m_run[r]);
                int csw = (f * 2 + (lc >> 3)) ^ lr;
                Ps[prow * 32 + (csw << 3) + (lc & 7)] = (F16)p;
            }
        }
        if (t == 0) rflag[(mt + 1) & 1] = 0;
        __syncthreads();                       // P + corr + flag visible

        // rescale acc only when some row actually rescaled this step
        if (rflag[mt & 1]) {
#pragma unroll
            for (int qf = 0; qf < 4; qf++) {
                f32x4 c4 = *(f32x4*)&crl[qf * 16 + lr * 4];
#pragma unroll
                for (int fv = 0; fv < 4; fv++)
#pragma unroll
                    for (int rr = 0; rr < 4; rr++)
                        acc[qf][fv][rr] *= c4[rr];
            }
        }

        // PV (wave's v-slice over all 64 q-rows, contraction 32) + l-sum MFMA
        {
            f16x8 pown = *(f16x8*)&Ps[(w * 16 + lc) * 32 + ((lr ^ pswz) << 3)];
            lsum = __builtin_amdgcn_mfma_f32_16x16x32_f16(pown, one8, lsum, 0, 0, 0);
            f16x8 pa[4];
#pragma unroll
            for (int qf = 0; qf < 4; qf++)
                pa[qf] = *(f16x8*)&Ps[(qf * 16 + lc) * 32 + ((lr ^ pswz) << 3)];
#pragma unroll
            for (int fv = 0; fv < 4; fv++) {
                f16x8 bb = *(f16x8*)&Vl[(vs + fv * 16 + lc) * 32 + (lr << 3)];
#pragma unroll
                for (int qf = 0; qf < 4; qf++)
                    acc[qf][fv] = __builtin_amdgcn_mfma_f32_16x16x32_f16(pa[qf], bb, acc[qf][fv], 0, 0, 0);
            }
        }
    }

    // epilogue: share l, then write normalized partial + L
    __syncthreads();
    if (lc == 0) {
#pragma unroll
        for (int r = 0; r < 4; r++) crl[w * 16 + lr * 4 + r] = lsum[r];
    }
    __syncthreads();

    F16* cb = parts + (size_t)kset * PSET + (size_t)b * NN * KCH;
#pragma unroll
    for (int qf = 0; qf < 4; qf++) {
        f32x4 l4 = *(f32x4*)&crl[qf * 16 + lr * 4];
#pragma unroll
        for (int r = 0; r < 4; r++) {
            int n = n0 + qf * 16 + lr * 4 + r;
            float inv = 1.0f / l4[r];
#pragma unroll
            for (int fv = 0; fv < 4; fv++)
                cb[(size_t)n * KCH + vs + fv * 16 + lc] = (F16)(acc[qf][fv][r] * inv);
        }
    }
    float* Lb = Lbuf + ((size_t)kset * NB + b) * NN;
    if (lc == 0) {
#pragma unroll
        for (int r = 0; r < 4; r++)
            Lb[n0 + w * 16 + lr * 4 + r] = m_run[r] + __logf(lsum[r]);
    }
}

// ---------------------------------------------------------------- out GEMM (fused 4-way split-K merge)
__global__ __launch_bounds__(256) void k_out_gemm(const F16* __restrict__ parts,
                                                  const float* __restrict__ Lbuf,
                                                  const float* __restrict__ w_w,
                                                  const float* __restrict__ w_b,
                                                  float* __restrict__ out) {
    __shared__ F16 Al[128][40];
    __shared__ F16 Bl[128][40];
    __shared__ float lw[4][128];
    int b = blockIdx.z;
    int m0 = blockIdx.y * 128;
    int n0 = blockIdx.x * 128;
    int t = threadIdx.x, w = t >> 6, l = t & 63;
    int wr = w >> 1, wc = w & 1;
    int lr = l >> 4, lc = l & 15;

    if (t < 128) {
        int n = n0 + t;
        float L0 = Lbuf[(size_t)b * NN + n];
        float L1 = Lbuf[(size_t)NBNN + (size_t)b * NN + n];
        float L2 = Lbuf[2 * (size_t)NBNN + (size_t)b * NN + n];
        float L3 = Lbuf[3 * (size_t)NBNN + (size_t)b * NN + n];
        float M = fmaxf(fmaxf(L0, L1), fmaxf(L2, L3));
        float e0 = __expf(L0 - M), e1 = __expf(L1 - M);
        float e2 = __expf(L2 - M), e3 = __expf(L3 - M);
        float inv = 1.0f / (e0 + e1 + e2 + e3);
        lw[0][t] = e0 * inv; lw[1][t] = e1 * inv;
        lw[2][t] = e2 * inv; lw[3][t] = e3 * inv;
    }
    __syncthreads();
    int row0 = t >> 2, row1 = (t >> 2) + 64;
    float wA0 = lw[0][row0], wA1 = lw[1][row0], wA2 = lw[2][row0], wA3 = lw[3][row0];
    float wB0 = lw[0][row1], wB1 = lw[1][row1], wB2 = lw[2][row1], wB3 = lw[3][row1];

    f32x4 acc[4][4];
    const f32x4 fz = {0.f, 0.f, 0.f, 0.f};
#pragma unroll
    for (int i = 0; i < 4; i++)
#pragma unroll
        for (int j = 0; j < 4; j++) acc[i][j] = fz;

    for (int kt = 0; kt < KCH / 32; kt++) {
        int c0 = kt * 32;
        __syncthreads();
#pragma unroll
        for (int p = 0; p < 4; p++) {
            int row = (t >> 3) + p * 32;
            int cc = (t & 7) * 4;
            float4 v = *(const float4*)&w_w[(size_t)(m0 + row) * KCH + c0 + cc];
            f16x4 h; h[0] = (F16)v.x; h[1] = (F16)v.y; h[2] = (F16)v.z; h[3] = (F16)v.w;
            *(f16x4*)&Al[row][cc] = h;
        }
#pragma unroll
        for (int p = 0; p < 2; p++) {
            int row = (p == 0) ? row0 : row1;
            float u0 = (p == 0) ? wA0 : wB0, u1 = (p == 0) ? wA1 : wB1;
            float u2 = (p == 0) ? wA2 : wB2, u3 = (p == 0) ? wA3 : wB3;
            int cc = (t & 3) * 8;
            size_t base = ((size_t)b * NN + n0 + row) * KCH + c0 + cc;
            f16x8 p0 = *(const f16x8*)&parts[base];
            f16x8 p1 = *(const f16x8*)&parts[PSET + base];
            f16x8 p2 = *(const f16x8*)&parts[2 * PSET + base];
            f16x8 p3 = *(const f16x8*)&parts[3 * PSET + base];
            f16x8 m;
#pragma unroll
            for (int j = 0; j < 8; j++)
                m[j] = (F16)(u0 * (float)p0[j] + u1 * (float)p1[j] +
                             u2 * (float)p2[j] + u3 * (float)p3[j]);
            *(f16x8*)&Bl[row][cc] = m;
        }
        __syncthreads();
        f16x8 a[4];
#pragma unroll
        for (int fi = 0; fi < 4; fi++)
            a[fi] = *(f16x8*)&Al[wr * 64 + fi * 16 + lc][lr * 8];
#pragma unroll
        for (int fj = 0; fj < 4; fj++) {
            f16x8 bb = *(f16x8*)&Bl[wc * 64 + fj * 16 + lc][lr * 8];
#pragma unroll
            for (int fi = 0; fi < 4; fi++)
                acc[fi][fj] = __builtin_amdgcn_mfma_f32_16x16x32_f16(a[fi], bb, acc[fi][fj], 0, 0, 0);
        }
    }

#pragma unroll
    for (int fi = 0; fi < 4; fi++) {
        int o0 = m0 + wr * 64 + fi * 16 + lr * 4;
#pragma unroll
        for (int fj = 0; fj < 4; fj++) {
            int n = n0 + wc * 64 + fj * 16 + lc;
#pragma unroll
            for (int r = 0; r < 4; r++) {
                out[((size_t)b * OCH + o0 + r) * NN + n] = acc[fi][fj][r] + w_b[o0 + r];
            }
        }
    }
}

// ---------------------------------------------------------------- launch
extern "C" void kernel_launch(void* const* d_in, const int* in_sizes, int n_in,
                              void* d_out, int out_size, void* d_ws, size_t ws_size,
                              hipStream_t stream) {
    const float* x       = (const float*)d_in[0];
    const float* key_w   = (const float*)d_in[1];
    const float* key_b   = (const float*)d_in[2];
    const float* gamma   = (const float*)d_in[3];
    const float* beta    = (const float*)d_in[4];
    const float* mean    = (const float*)d_in[5];
    const float* var     = (const float*)d_in[6];
    const float* value_w = (const float*)d_in[7];
    const float* value_b = (const float*)d_in[8];
    const float* w_w     = (const float*)d_in[9];
    const float* w_b     = (const float*)d_in[10];
    float* out = (float*)d_out;
    char* ws = (char*)d_ws;

    // layout (ws >= 50.59 MB proven in R4's 4-set run):
    // parts 4*8.39M (overlays dead xT) | KQt 8.39M | Vg 8.39M | L 256K
    size_t kqt_off = 4 * PSET * 2;
    size_t vg_off  = kqt_off + 8388608ull;
    size_t l_off   = vg_off + 8388608ull;

    F16*   xT    = (F16*)(ws);
    F16*   parts = (F16*)(ws);
    F16*   KQt   = (F16*)(ws + kqt_off);
    F16*   Vg    = (F16*)(ws + vg_off);
    float* Lbuf  = (float*)(ws + l_off);

    hipLaunchKernelGGL(k_transpose, dim3(8, 64, 4), dim3(256), 0, stream, x, xT);
    hipLaunchKernelGGL(k_kv_gemm, dim3(32, 4, 4), dim3(256), 0, stream,
                       xT, key_w, key_b, gamma, beta, mean, var, value_w, value_b, KQt, Vg);
    hipLaunchKernelGGL(k_flash, dim3(1024), dim3(256), 0, stream, KQt, Vg, parts, Lbuf);
    hipLaunchKernelGGL(k_out_gemm, dim3(32, 4, 4), dim3(256), 0, stream,
                       parts, Lbuf, w_w, w_b, out);
}

// Round 10
// 161.873 us; speedup vs baseline: 1.8733x; 1.8733x over previous
//
#include <hip/hip_runtime.h>

#define F16 _Float16
typedef _Float16 f16x8 __attribute__((ext_vector_type(8)));
typedef _Float16 f16x4 __attribute__((ext_vector_type(4)));
typedef float f32x4 __attribute__((ext_vector_type(4)));

#define NB    4
#define CIN   512
#define NN    4096
#define KCH   256
#define OCH   512
#define BNEPS 1e-5f
#define PSET  ((size_t)NB * NN * KCH)        // elements per partial set
#define NBNN  (NB * NN)

// async global->LDS, 16B per lane (dest = uniform base + lane*16)
__device__ __forceinline__ void gl16(const F16* g, F16* l) {
    __builtin_amdgcn_global_load_lds((const __attribute__((address_space(1))) void*)g,
                                     (__attribute__((address_space(3))) void*)l, 16, 0, 0);
}

// ---------------------------------------------------------------- transpose
__global__ __launch_bounds__(256) void k_transpose(const float* __restrict__ x,
                                                   F16* __restrict__ xT) {
    __shared__ float tile[64][65];
    int b = blockIdx.z, n0 = blockIdx.y * 64, c0 = blockIdx.x * 64;
    int t = threadIdx.x;
    const float* xb = x + (size_t)b * CIN * NN;
#pragma unroll
    for (int i = 0; i < 4; i++) {
        int c = (t >> 4) + i * 16;
        int n = (t & 15) * 4;
        float4 v = *(const float4*)&xb[(size_t)(c0 + c) * NN + n0 + n];
        tile[c][n + 0] = v.x; tile[c][n + 1] = v.y;
        tile[c][n + 2] = v.z; tile[c][n + 3] = v.w;
    }
    __syncthreads();
    F16* xTb = xT + (size_t)b * NN * CIN;
#pragma unroll
    for (int i = 0; i < 4; i++) {
        int n = (t >> 4) + i * 16;
        int c = (t & 15) * 4;
        f16x4 o;
        o[0] = (F16)tile[c + 0][n]; o[1] = (F16)tile[c + 1][n];
        o[2] = (F16)tile[c + 2][n]; o[3] = (F16)tile[c + 3][n];
        *(f16x4*)&xTb[(size_t)(n0 + n) * CIN + c0 + c] = o;
    }
}

// ---------------------------------------------------------------- K/V GEMM
__global__ __launch_bounds__(256) void k_kv_gemm(
    const F16* __restrict__ xT,
    const float* __restrict__ key_w, const float* __restrict__ key_b,
    const float* __restrict__ gamma, const float* __restrict__ beta,
    const float* __restrict__ mean,  const float* __restrict__ var,
    const float* __restrict__ value_w, const float* __restrict__ value_b,
    F16* __restrict__ KQt, F16* __restrict__ Vg) {
    __shared__ F16 Al[128][40];
    __shared__ F16 Bl[128][40];
    int b = blockIdx.z;
    int m0 = blockIdx.y * 128;
    int n0 = blockIdx.x * 128;
    int t = threadIdx.x, w = t >> 6, l = t & 63;
    int wr = w >> 1, wc = w & 1;
    int lr = l >> 4, lc = l & 15;
    f32x4 acc[4][4];
    const f32x4 fz = {0.f, 0.f, 0.f, 0.f};
#pragma unroll
    for (int i = 0; i < 4; i++)
#pragma unroll
        for (int j = 0; j < 4; j++) acc[i][j] = fz;
    const F16* xb = xT + (size_t)b * NN * CIN;

    for (int kt = 0; kt < CIN / 32; kt++) {
        int c0 = kt * 32;
        __syncthreads();
#pragma unroll
        for (int p = 0; p < 4; p++) {
            int row = (t >> 3) + p * 32;
            int cc = (t & 7) * 4;
            int rg = m0 + row;
            const float* src = (rg < 256) ? (key_w + (size_t)rg * CIN)
                                          : (value_w + (size_t)(rg - 256) * CIN);
            float4 v = *(const float4*)&src[c0 + cc];
            f16x4 h; h[0] = (F16)v.x; h[1] = (F16)v.y; h[2] = (F16)v.z; h[3] = (F16)v.w;
            *(f16x4*)&Al[row][cc] = h;
        }
#pragma unroll
        for (int p = 0; p < 2; p++) {
            int row = (t >> 2) + p * 64;
            int cc = (t & 3) * 8;
            *(int4*)&Bl[row][cc] = *(const int4*)&xb[(size_t)(n0 + row) * CIN + c0 + cc];
        }
        __syncthreads();
        f16x8 a[4];
#pragma unroll
        for (int fi = 0; fi < 4; fi++)
            a[fi] = *(f16x8*)&Al[wr * 64 + fi * 16 + lc][lr * 8];
#pragma unroll
        for (int fj = 0; fj < 4; fj++) {
            f16x8 bb = *(f16x8*)&Bl[wc * 64 + fj * 16 + lc][lr * 8];
#pragma unroll
            for (int fi = 0; fi < 4; fi++)
                acc[fi][fj] = __builtin_amdgcn_mfma_f32_16x16x32_f16(a[fi], bb, acc[fi][fj], 0, 0, 0);
        }
    }

    if (m0 < 256) {
#pragma unroll
        for (int fi = 0; fi < 4; fi++) {
            int ch0 = m0 + wr * 64 + fi * 16 + lr * 4;
            float invs[4], mns[4], bts[4], kbs[4];
#pragma unroll
            for (int r = 0; r < 4; r++) {
                int ch = ch0 + r;
                invs[r] = gamma[ch] * rsqrtf(var[ch] + BNEPS);
                mns[r] = mean[ch]; bts[r] = beta[ch]; kbs[r] = key_b[ch];
            }
#pragma unroll
            for (int fj = 0; fj < 4; fj++) {
                int n = n0 + wc * 64 + fj * 16 + lc;
                f16x4 o;
#pragma unroll
                for (int r = 0; r < 4; r++) {
                    float v = (acc[fi][fj][r] + kbs[r] - mns[r]) * invs[r] + bts[r];
                    v = fmaxf(v, 0.0f);
                    o[r] = (F16)v;
                }
                *(f16x4*)&KQt[((size_t)b * NN + n) * KCH + ch0] = o;
            }
        }
    } else {
#pragma unroll
        for (int fi = 0; fi < 4; fi++) {
            int v0 = m0 - 256 + wr * 64 + fi * 16 + lr * 4;
#pragma unroll
            for (int fj = 0; fj < 4; fj++) {
                int n = n0 + wc * 64 + fj * 16 + lc;
#pragma unroll
                for (int r = 0; r < 4; r++) {
                    float vv = acc[fi][fj][r] + value_b[v0 + r];
                    Vg[((size_t)b * KCH + v0 + r) * NN + n] = (F16)vv;
                }
            }
        }
    }
}

// ---------------------------------------------------------------- flash attention
// KVBLK=32, double-buffered K/V via global_load_lds prefetch (issue after the
// P-barrier, drained by the end-of-loop barrier -> latency hidden under PV+QK).
// 512 blocks = 2/CU (LDS 68.3 KB), split-K S=2, 2 key-streams per XCD (R8
// regime). Q in regs; PV split by v-slice; l via MFMA; defer-max + rflag skip.
__global__ __launch_bounds__(256, 2) void k_flash(const F16* __restrict__ KQt,
                                                  const F16* __restrict__ Vg,
                                                  F16* __restrict__ parts,
                                                  float* __restrict__ Lbuf) {
    __shared__ __align__(16) F16 Kl[2][32 * 256];   // 2 x 16 KB, row 512B
    __shared__ __align__(16) F16 Vl[2][256 * 32];   // 2 x 16 KB, row 64B
    __shared__ __align__(16) F16 Ps[64 * 32];       // 4 KB, row 64B
    __shared__ __align__(16) float crl[64];
    __shared__ int rflag[2];
    int bid = blockIdx.x;
    int xcd = bid & 7;
    int b = xcd >> 1;                          // batch pinned to an XCD pair
    int hi = bid >> 3;                         // 0..63
    int kset = hi & 1;                         // 2 key-streams per XCD
    int qtile = (xcd & 1) * 32 + (hi >> 1);    // 0..63
    int n0 = qtile * 64;
    int kbase = kset * 2048;
    int t = threadIdx.x, w = t >> 6, l = t & 63;
    int lr = l >> 4, lc = l & 15;
    int kx = lc & 7;                           // K read XOR (row&7 congruent)
    int pswz = (lc >> 2) & 3;                  // P read XOR ((row>>2)&3 congruent)
    int vs = w * 64;                           // wave's v-slice for PV
    const F16* kqb = KQt + (size_t)b * NN * KCH;
    const F16* vgb = Vg + (size_t)b * KCH * NN;
    const float scale = 0.0625f;

    if (t == 0) { rflag[0] = 0; rflag[1] = 0; }

    // Q tile -> registers (A-frag: row = w*16+lc, c-cols = cs*32 + lr*8)
    f16x8 qreg[8];
    {
        const F16* qrow = kqb + (size_t)(n0 + w * 16 + lc) * KCH + lr * 8;
#pragma unroll
        for (int cs = 0; cs < 8; cs++)
            qreg[cs] = *(const f16x8*)&qrow[cs * 32];
    }
    f16x8 one8;
#pragma unroll
    for (int j = 0; j < 8; j++) one8[j] = (F16)1.0f;

    f32x4 acc[4][4];                           // [qf][fv]: 64 q-rows x 64 v-slice
    const f32x4 fz = {0.f, 0.f, 0.f, 0.f};
#pragma unroll
    for (int i = 0; i < 4; i++)
#pragma unroll
        for (int j = 0; j < 4; j++) acc[i][j] = fz;
    f32x4 lsum = fz;
    float m_run[4] = {-1e30f, -1e30f, -1e30f, -1e30f};

    // staging lane constants
    int khalf = l >> 5;                        // K: row within pair
    int kc = l & 31;                           // K chunk slot (16B)
    int vloc = l >> 2;                         // V: row within 16-row group
    int vc = l & 3;                            // V chunk slot

    // prologue: stage tile 0 into buffer 0
    {
#pragma unroll
        for (int p = 0; p < 4; p++) {
            int row = w * 8 + 2 * p + khalf;
            gl16(kqb + (size_t)(kbase + row) * KCH + (kc ^ (row & 7)) * 8,
                 &Kl[0][(w * 8 + 2 * p) * 256]);
        }
#pragma unroll
        for (int p = 0; p < 4; p++) {
            int row = w * 64 + p * 16 + vloc;
            gl16(vgb + (size_t)row * NN + kbase + vc * 8,
                 &Vl[0][(w * 64 + p * 16) * 32]);
        }
    }
    __syncthreads();                           // tile 0 visible

    for (int mt = 0; mt < 64; mt++) {
        int cur = mt & 1, nxt = cur ^ 1;

        // S = Q K^T (wave: 16 q-rows x 32 k-cols, contraction 256)
        f32x4 s[2];
        s[0] = fz; s[1] = fz;
#pragma unroll
        for (int cs = 0; cs < 8; cs++) {
#pragma unroll
            for (int f = 0; f < 2; f++) {
                f16x8 bb = *(f16x8*)&Kl[cur][(f * 16 + lc) * 256 + (((cs * 4 + lr) ^ kx) << 3)];
                s[f] = __builtin_amdgcn_mfma_f32_16x16x32_f16(qreg[cs], bb, s[f], 0, 0, 0);
            }
        }

        // defer-max online softmax: lane-local guard, rare wave-reduce path
        float lm[4], cr[4];
#pragma unroll
        for (int r = 0; r < 4; r++) {
            lm[r] = fmaxf(s[0][r], s[1][r]) * scale;
            cr[r] = 1.0f;
        }
        int ok = (lm[0] <= m_run[0] + 8.0f) && (lm[1] <= m_run[1] + 8.0f) &&
                 (lm[2] <= m_run[2] + 8.0f) && (lm[3] <= m_run[3] + 8.0f);
        if (!__all(ok)) {
#pragma unroll
            for (int r = 0; r < 4; r++) {
                float mx = lm[r];
#pragma unroll
                for (int off = 1; off < 16; off <<= 1)
                    mx = fmaxf(mx, __shfl_xor(mx, off, 64));
                float mnew = fmaxf(m_run[r], mx);
                cr[r] = __expf(m_run[r] - mnew);
                m_run[r] = mnew;
                lsum[r] *= cr[r];
            }
            if (l == 0) rflag[cur] = 1;
        }
        if (lc == 0) {
#pragma unroll
            for (int r = 0; r < 4; r++) crl[w * 16 + lr * 4 + r] = cr[r];
        }
        // P = exp(s*scale - m_run) -> Ps, chunk XOR by (prow>>2)&3 (= lr here)
#pragma unroll
        for (int r = 0; r < 4; r++) {
            int prow = w * 16 + lr * 4 + r;
#pragma unroll
            for (int f = 0; f < 2; f++) {
                float p = __expf(s[f][r] * scale - m_run[r]);
                int csw = (f * 2 + (lc >> 3)) ^ lr;
                Ps[prow * 32 + (csw << 3) + (lc & 7)] = (F16)p;
            }
        }
        if (t == 0) rflag[nxt] = 0;
        __syncthreads();                       // B1: P + crl + flags visible

        // prefetch tile mt+1 into the spare buffer (drains at B2, under compute)
        if (mt < 63) {
            int m0n = kbase + (mt + 1) * 32;
#pragma unroll
            for (int p = 0; p < 4; p++) {
                int row = w * 8 + 2 * p + khalf;
                gl16(kqb + (size_t)(m0n + row) * KCH + (kc ^ (row & 7)) * 8,
                     &Kl[nxt][(w * 8 + 2 * p) * 256]);
            }
#pragma unroll
            for (int p = 0; p < 4; p++) {
                int row = w * 64 + p * 16 + vloc;
                gl16(vgb + (size_t)row * NN + m0n + vc * 8,
                     &Vl[nxt][(w * 64 + p * 16) * 32]);
            }
        }

        // rescale acc only when some row actually rescaled this step
        if (rflag[cur]) {
#pragma unroll
            for (int qf = 0; qf < 4; qf++) {
                f32x4 c4 = *(f32x4*)&crl[qf * 16 + lr * 4];
#pragma unroll
                for (int fv = 0; fv < 4; fv++)
#pragma unroll
                    for (int rr = 0; rr < 4; rr++)
                        acc[qf][fv][rr] *= c4[rr];
            }
        }

        // PV (wave's v-slice over all 64 q-rows, contraction 32) + l-sum MFMA
        {
            f16x8 pown = *(f16x8*)&Ps[(w * 16 + lc) * 32 + ((lr ^ pswz) << 3)];
            lsum = __builtin_amdgcn_mfma_f32_16x16x32_f16(pown, one8, lsum, 0, 0, 0);
            f16x8 pa[4];
#pragma unroll
            for (int qf = 0; qf < 4; qf++)
                pa[qf] = *(f16x8*)&Ps[(qf * 16 + lc) * 32 + ((lr ^ pswz) << 3)];
#pragma unroll
            for (int fv = 0; fv < 4; fv++) {
                f16x8 bb = *(f16x8*)&Vl[cur][(vs + fv * 16 + lc) * 32 + (lr << 3)];
#pragma unroll
                for (int qf = 0; qf < 4; qf++)
                    acc[qf][fv] = __builtin_amdgcn_mfma_f32_16x16x32_f16(pa[qf], bb, acc[qf][fv], 0, 0, 0);
            }
        }
        __syncthreads();                       // B2: prefetch drained; Ps reusable
    }

    // epilogue: share l, then write normalized partial + L
    if (lc == 0) {
#pragma unroll
        for (int r = 0; r < 4; r++) crl[w * 16 + lr * 4 + r] = lsum[r];
    }
    __syncthreads();

    F16* cb = parts + (size_t)kset * PSET + (size_t)b * NN * KCH;
#pragma unroll
    for (int qf = 0; qf < 4; qf++) {
        f32x4 l4 = *(f32x4*)&crl[qf * 16 + lr * 4];
#pragma unroll
        for (int r = 0; r < 4; r++) {
            int n = n0 + qf * 16 + lr * 4 + r;
            float inv = 1.0f / l4[r];
#pragma unroll
            for (int fv = 0; fv < 4; fv++)
                cb[(size_t)n * KCH + vs + fv * 16 + lc] = (F16)(acc[qf][fv][r] * inv);
        }
    }
    float* Lb = Lbuf + ((size_t)kset * NB + b) * NN;
    if (lc == 0) {
#pragma unroll
        for (int r = 0; r < 4; r++)
            Lb[n0 + w * 16 + lr * 4 + r] = m_run[r] + __logf(lsum[r]);
    }
}

// ---------------------------------------------------------------- out GEMM (fused split-K merge)
__global__ __launch_bounds__(256) void k_out_gemm(const F16* __restrict__ parts,
                                                  const float* __restrict__ Lbuf,
                                                  const float* __restrict__ w_w,
                                                  const float* __restrict__ w_b,
                                                  float* __restrict__ out) {
    __shared__ F16 Al[128][40];
    __shared__ F16 Bl[128][40];
    __shared__ float lw0[128], lw1[128];
    int b = blockIdx.z;
    int m0 = blockIdx.y * 128;
    int n0 = blockIdx.x * 128;
    int t = threadIdx.x, w = t >> 6, l = t & 63;
    int wr = w >> 1, wc = w & 1;
    int lr = l >> 4, lc = l & 15;

    if (t < 128) {
        int n = n0 + t;
        float L0 = Lbuf[(size_t)b * NN + n];
        float L1 = Lbuf[(size_t)NBNN + (size_t)b * NN + n];
        float M = fmaxf(L0, L1);
        float e0 = __expf(L0 - M), e1 = __expf(L1 - M);
        float inv = 1.0f / (e0 + e1);
        lw0[t] = e0 * inv; lw1[t] = e1 * inv;
    }
    __syncthreads();
    int row0 = t >> 2, row1 = (t >> 2) + 64;
    float w00 = lw0[row0], w10 = lw1[row0];
    float w01 = lw0[row1], w11 = lw1[row1];

    f32x4 acc[4][4];
    const f32x4 fz = {0.f, 0.f, 0.f, 0.f};
#pragma unroll
    for (int i = 0; i < 4; i++)
#pragma unroll
        for (int j = 0; j < 4; j++) acc[i][j] = fz;

    for (int kt = 0; kt < KCH / 32; kt++) {
        int c0 = kt * 32;
        __syncthreads();
#pragma unroll
        for (int p = 0; p < 4; p++) {
            int row = (t >> 3) + p * 32;
            int cc = (t & 7) * 4;
            float4 v = *(const float4*)&w_w[(size_t)(m0 + row) * KCH + c0 + cc];
            f16x4 h; h[0] = (F16)v.x; h[1] = (F16)v.y; h[2] = (F16)v.z; h[3] = (F16)v.w;
            *(f16x4*)&Al[row][cc] = h;
        }
#pragma unroll
        for (int p = 0; p < 2; p++) {
            int row = (p == 0) ? row0 : row1;
            float wa = (p == 0) ? w00 : w01;
            float wb2 = (p == 0) ? w10 : w11;
            int cc = (t & 3) * 8;
            size_t base = ((size_t)b * NN + n0 + row) * KCH + c0 + cc;
            f16x8 p0 = *(const f16x8*)&parts[base];
            f16x8 p1 = *(const f16x8*)&parts[PSET + base];
            f16x8 m;
#pragma unroll
            for (int j = 0; j < 8; j++)
                m[j] = (F16)(wa * (float)p0[j] + wb2 * (float)p1[j]);
            *(f16x8*)&Bl[row][cc] = m;
        }
        __syncthreads();
        f16x8 a[4];
#pragma unroll
        for (int fi = 0; fi < 4; fi++)
            a[fi] = *(f16x8*)&Al[wr * 64 + fi * 16 + lc][lr * 8];
#pragma unroll
        for (int fj = 0; fj < 4; fj++) {
            f16x8 bb = *(f16x8*)&Bl[wc * 64 + fj * 16 + lc][lr * 8];
#pragma unroll
            for (int fi = 0; fi < 4; fi++)
                acc[fi][fj] = __builtin_amdgcn_mfma_f32_16x16x32_f16(a[fi], bb, acc[fi][fj], 0, 0, 0);
        }
    }

#pragma unroll
    for (int fi = 0; fi < 4; fi++) {
        int o0 = m0 + wr * 64 + fi * 16 + lr * 4;
#pragma unroll
        for (int fj = 0; fj < 4; fj++) {
            int n = n0 + wc * 64 + fj * 16 + lc;
#pragma unroll
            for (int r = 0; r < 4; r++) {
                out[((size_t)b * OCH + o0 + r) * NN + n] = acc[fi][fj][r] + w_b[o0 + r];
            }
        }
    }
}

// ---------------------------------------------------------------- launch
extern "C" void kernel_launch(void* const* d_in, const int* in_sizes, int n_in,
                              void* d_out, int out_size, void* d_ws, size_t ws_size,
                              hipStream_t stream) {
    const float* x       = (const float*)d_in[0];
    const float* key_w   = (const float*)d_in[1];
    const float* key_b   = (const float*)d_in[2];
    const float* gamma   = (const float*)d_in[3];
    const float* beta    = (const float*)d_in[4];
    const float* mean    = (const float*)d_in[5];
    const float* var     = (const float*)d_in[6];
    const float* value_w = (const float*)d_in[7];
    const float* value_b = (const float*)d_in[8];
    const float* w_w     = (const float*)d_in[9];
    const float* w_b     = (const float*)d_in[10];
    float* out = (float*)d_out;
    char* ws = (char*)d_ws;

    // layout: parts 2*8.39M (overlays dead xT) | KQt 8.39M | Vg 8.39M | L 128K
    size_t kqt_off = 2 * PSET * 2;
    size_t vg_off  = kqt_off + 8388608ull;
    size_t l_off   = vg_off + 8388608ull;

    F16*   xT    = (F16*)(ws);
    F16*   parts = (F16*)(ws);
    F16*   KQt   = (F16*)(ws + kqt_off);
    F16*   Vg    = (F16*)(ws + vg_off);
    float* Lbuf  = (float*)(ws + l_off);

    hipLaunchKernelGGL(k_transpose, dim3(8, 64, 4), dim3(256), 0, stream, x, xT);
    hipLaunchKernelGGL(k_kv_gemm, dim3(32, 4, 4), dim3(256), 0, stream,
                       xT, key_w, key_b, gamma, beta, mean, var, value_w, value_b, KQt, Vg);
    hipLaunchKernelGGL(k_flash, dim3(512), dim3(256), 0, stream, KQt, Vg, parts, Lbuf);
    hipLaunchKernelGGL(k_out_gemm, dim3(32, 4, 4), dim3(256), 0, stream,
                       parts, Lbuf, w_w, w_b, out);
}

// Round 11
// 153.651 us; speedup vs baseline: 1.9735x; 1.0535x over previous
//
#include <hip/hip_runtime.h>

#define F16 _Float16
typedef _Float16 f16x8 __attribute__((ext_vector_type(8)));
typedef _Float16 f16x4 __attribute__((ext_vector_type(4)));
typedef float f32x4 __attribute__((ext_vector_type(4)));
typedef float f32x16 __attribute__((ext_vector_type(16)));

#define NB    4
#define CIN   512
#define NN    4096
#define KCH   256
#define OCH   512
#define BNEPS 1e-5f
#define PSET  ((size_t)NB * NN * KCH)        // elements per partial set
#define NBNN  (NB * NN)

// async global->LDS, 16B per lane (dest = wave-uniform base + lane*16)
__device__ __forceinline__ void gl16(const F16* g, F16* l) {
    __builtin_amdgcn_global_load_lds((const __attribute__((address_space(1))) void*)g,
                                     (__attribute__((address_space(3))) void*)l, 16, 0, 0);
}

// ---------------------------------------------------------------- transpose
__global__ __launch_bounds__(256) void k_transpose(const float* __restrict__ x,
                                                   F16* __restrict__ xT) {
    __shared__ float tile[64][65];
    int b = blockIdx.z, n0 = blockIdx.y * 64, c0 = blockIdx.x * 64;
    int t = threadIdx.x;
    const float* xb = x + (size_t)b * CIN * NN;
#pragma unroll
    for (int i = 0; i < 4; i++) {
        int c = (t >> 4) + i * 16;
        int n = (t & 15) * 4;
        float4 v = *(const float4*)&xb[(size_t)(c0 + c) * NN + n0 + n];
        tile[c][n + 0] = v.x; tile[c][n + 1] = v.y;
        tile[c][n + 2] = v.z; tile[c][n + 3] = v.w;
    }
    __syncthreads();
    F16* xTb = xT + (size_t)b * NN * CIN;
#pragma unroll
    for (int i = 0; i < 4; i++) {
        int n = (t >> 4) + i * 16;
        int c = (t & 15) * 4;
        f16x4 o;
        o[0] = (F16)tile[c + 0][n]; o[1] = (F16)tile[c + 1][n];
        o[2] = (F16)tile[c + 2][n]; o[3] = (F16)tile[c + 3][n];
        *(f16x4*)&xTb[(size_t)(n0 + n) * CIN + c0 + c] = o;
    }
}

// ---------------------------------------------------------------- K/V GEMM
__global__ __launch_bounds__(256) void k_kv_gemm(
    const F16* __restrict__ xT,
    const float* __restrict__ key_w, const float* __restrict__ key_b,
    const float* __restrict__ gamma, const float* __restrict__ beta,
    const float* __restrict__ mean,  const float* __restrict__ var,
    const float* __restrict__ value_w, const float* __restrict__ value_b,
    F16* __restrict__ KQt, F16* __restrict__ Vg) {
    __shared__ F16 Al[128][40];
    __shared__ F16 Bl[128][40];
    int b = blockIdx.z;
    int m0 = blockIdx.y * 128;
    int n0 = blockIdx.x * 128;
    int t = threadIdx.x, w = t >> 6, l = t & 63;
    int wr = w >> 1, wc = w & 1;
    int lr = l >> 4, lc = l & 15;
    f32x4 acc[4][4];
    const f32x4 fz = {0.f, 0.f, 0.f, 0.f};
#pragma unroll
    for (int i = 0; i < 4; i++)
#pragma unroll
        for (int j = 0; j < 4; j++) acc[i][j] = fz;
    const F16* xb = xT + (size_t)b * NN * CIN;

    for (int kt = 0; kt < CIN / 32; kt++) {
        int c0 = kt * 32;
        __syncthreads();
#pragma unroll
        for (int p = 0; p < 4; p++) {
            int row = (t >> 3) + p * 32;
            int cc = (t & 7) * 4;
            int rg = m0 + row;
            const float* src = (rg < 256) ? (key_w + (size_t)rg * CIN)
                                          : (value_w + (size_t)(rg - 256) * CIN);
            float4 v = *(const float4*)&src[c0 + cc];
            f16x4 h; h[0] = (F16)v.x; h[1] = (F16)v.y; h[2] = (F16)v.z; h[3] = (F16)v.w;
            *(f16x4*)&Al[row][cc] = h;
        }
#pragma unroll
        for (int p = 0; p < 2; p++) {
            int row = (t >> 2) + p * 64;
            int cc = (t & 3) * 8;
            *(int4*)&Bl[row][cc] = *(const int4*)&xb[(size_t)(n0 + row) * CIN + c0 + cc];
        }
        __syncthreads();
        f16x8 a[4];
#pragma unroll
        for (int fi = 0; fi < 4; fi++)
            a[fi] = *(f16x8*)&Al[wr * 64 + fi * 16 + lc][lr * 8];
#pragma unroll
        for (int fj = 0; fj < 4; fj++) {
            f16x8 bb = *(f16x8*)&Bl[wc * 64 + fj * 16 + lc][lr * 8];
#pragma unroll
            for (int fi = 0; fi < 4; fi++)
                acc[fi][fj] = __builtin_amdgcn_mfma_f32_16x16x32_f16(a[fi], bb, acc[fi][fj], 0, 0, 0);
        }
    }

    if (m0 < 256) {
#pragma unroll
        for (int fi = 0; fi < 4; fi++) {
            int ch0 = m0 + wr * 64 + fi * 16 + lr * 4;
            float invs[4], mns[4], bts[4], kbs[4];
#pragma unroll
            for (int r = 0; r < 4; r++) {
                int ch = ch0 + r;
                invs[r] = gamma[ch] * rsqrtf(var[ch] + BNEPS);
                mns[r] = mean[ch]; bts[r] = beta[ch]; kbs[r] = key_b[ch];
            }
#pragma unroll
            for (int fj = 0; fj < 4; fj++) {
                int n = n0 + wc * 64 + fj * 16 + lc;
                f16x4 o;
#pragma unroll
                for (int r = 0; r < 4; r++) {
                    float v = (acc[fi][fj][r] + kbs[r] - mns[r]) * invs[r] + bts[r];
                    v = fmaxf(v, 0.0f);
                    o[r] = (F16)v;
                }
                *(f16x4*)&KQt[((size_t)b * NN + n) * KCH + ch0] = o;
            }
        }
    } else {
#pragma unroll
        for (int fi = 0; fi < 4; fi++) {
            int v0 = m0 - 256 + wr * 64 + fi * 16 + lr * 4;
#pragma unroll
            for (int fj = 0; fj < 4; fj++) {
                int n = n0 + wc * 64 + fj * 16 + lc;
#pragma unroll
                for (int r = 0; r < 4; r++) {
                    float vv = acc[fi][fj][r] + value_b[v0 + r];
                    Vg[((size_t)b * KCH + v0 + r) * NN + n] = (F16)vv;
                }
            }
        }
    }
}

// ---------------------------------------------------------------- row norms + batch max
// Mrow[b*N+n] = ||kq_n||; Mb[b] = max_n ||kq_n|| (positive-float atomicMax via int)
__global__ __launch_bounds__(256) void k_rowmax(const F16* __restrict__ KQt,
                                                float* __restrict__ Mrow,
                                                float* __restrict__ MbA) {
    __shared__ float wmax[4];
    int t = threadIdx.x;
    int r = blockIdx.x * 64 + (t >> 2);
    int part = t & 3;
    const F16* rp = KQt + (size_t)r * KCH + part * 64;
    float ss = 0.f;
#pragma unroll
    for (int i = 0; i < 8; i++) {
        f16x8 v = *(const f16x8*)&rp[i * 8];
#pragma unroll
        for (int j = 0; j < 8; j++) { float f = (float)v[j]; ss = fmaf(f, f, ss); }
    }
    ss += __shfl_xor(ss, 1, 64);
    ss += __shfl_xor(ss, 2, 64);
    float norm = sqrtf(ss);
    if (part == 0) Mrow[r] = norm;
    float mx = norm;
#pragma unroll
    for (int off = 4; off < 64; off <<= 1) mx = fmaxf(mx, __shfl_xor(mx, off, 64));
    if ((t & 63) == 0) wmax[t >> 6] = mx;
    __syncthreads();
    if (t == 0) {
        float m = fmaxf(fmaxf(wmax[0], wmax[1]), fmaxf(wmax[2], wmax[3]));
        atomicMax((int*)&MbA[blockIdx.x >> 6], __float_as_int(m));
    }
}

// ---------------------------------------------------------------- flash attention
// 32x32x16 MFMA + FIXED per-row softmax bound m_n = ||kq_n||*Mb/16 (no online
// max, no rescale). Block = 64 q-rows, KVBLK=64, split-K S=2, 512 blocks =
// 2/CU (LDS 72.3 KB). 4 waves: QK (qg=w>>1, kh=w&1) 32x32 fragments; PV split
// by 64-v slice. All LDS tiles chunk-XOR swizzled by row&7 (both sides).
__global__ __launch_bounds__(256, 2) void k_flash(const F16* __restrict__ KQt,
                                                  const F16* __restrict__ Vg,
                                                  const float* __restrict__ Mrow,
                                                  const float* __restrict__ MbA,
                                                  F16* __restrict__ parts,
                                                  float* __restrict__ Lbuf) {
    __shared__ __align__(16) F16 Kl[64 * 256];    // 32 KB, row 512 B (32 chunks)
    __shared__ __align__(16) F16 Vl[256 * 64];    // 32 KB, row 128 B (8 chunks)
    __shared__ __align__(16) F16 Ps[64 * 64];     //  8 KB, row 128 B (8 chunks)
    __shared__ __align__(16) float crl[64];
    int bid = blockIdx.x;
    int xcd = bid & 7;
    int b = xcd >> 1;                          // batch pinned to an XCD pair
    int hi = bid >> 3;                         // 0..63
    int kset = hi & 1;                         // 2 key-streams per XCD
    int qtile = (xcd & 1) * 32 + (hi >> 1);    // 0..63
    int n0 = qtile * 64;
    int kbase = kset * 2048;
    int t = threadIdx.x, w = t >> 6, l = t & 63;
    int l31 = l & 31, lh = l >> 5;
    int x7 = l31 & 7;                          // row&7 for all fragment-read rows
    int qg = w >> 1, kh = w & 1;
    const F16* kqb = KQt + (size_t)b * NN * KCH;
    const F16* vgb = Vg + (size_t)b * KCH * NN;
    const float scale = 0.0625f;

    // Q A-fragments: q-row = n0 + qg*32 + l31; c-chunk cs: elems cs*16 + lh*8
    f16x8 qA[16];
    {
        const F16* qp = kqb + (size_t)(n0 + qg * 32 + l31) * KCH + lh * 8;
#pragma unroll
        for (int cs = 0; cs < 16; cs++) qA[cs] = *(const f16x8*)&qp[cs * 16];
    }
    // fixed softmax bound for this wave's 16 S-rows (D-layout rows)
    float mbv = MbA[b] * scale;
    f32x4 m4[4];
    {
        const float* mp = Mrow + (size_t)b * NN + n0 + qg * 32 + lh * 4;
#pragma unroll
        for (int g = 0; g < 4; g++) {
            f32x4 v = *(const f32x4*)&mp[g * 8];
#pragma unroll
            for (int j = 0; j < 4; j++) m4[g][j] = v[j] * mbv;
        }
    }
    f16x8 one8;
#pragma unroll
    for (int j = 0; j < 8; j++) one8[j] = (F16)1.0f;

    f32x16 acc[2][2] = {};                     // [qg2][vh]: 64q x (w's 64-v slice)
    f32x16 lsum = {};                          // waves 0,2: row sums for qg 0,1

    for (int mt = 0; mt < 32; mt++) {
        int m0 = kbase + mt * 64;
        __syncthreads();                       // all waves done with Kl/Vl (prev)
        // stage K tile [64 keys][256 c], pre-swizzled source chunks
#pragma unroll
        for (int c = 0; c < 8; c++) {
            int row = c * 8 + (t >> 5);
            gl16(kqb + (size_t)(m0 + row) * KCH + ((t & 31) ^ (t >> 5)) * 8,
                 &Kl[c * 2048 + w * 512]);
        }
        // stage V tile [256 v][64 keys]
#pragma unroll
        for (int c = 0; c < 8; c++) {
            int vrow = c * 32 + (t >> 3);
            gl16(vgb + (size_t)vrow * NN + m0 + ((t & 7) ^ ((t >> 3) & 7)) * 8,
                 &Vl[c * 2048 + w * 512]);
        }
        __syncthreads();                       // drain -> tiles visible

        // S(32q x 32k) for (qg, kh): contraction 256 = 16 MFMAs
        f32x16 s = {};
#pragma unroll
        for (int cs = 0; cs < 16; cs++) {
            int key = kh * 32 + l31;
            f16x8 kB = *(f16x8*)&Kl[key * 256 + (((cs * 2 + lh) ^ x7) * 8)];
            s = __builtin_amdgcn_mfma_f32_32x32x16_f16(qA[cs], kB, s, 0, 0, 0);
        }

        // P = exp(S*scale - m_row) -> Ps (swizzled); rows (r&3)+8*(r>>2)+4*lh
#pragma unroll
        for (int r = 0; r < 16; r++) {
            int row = qg * 32 + (r & 3) + 8 * (r >> 2) + 4 * lh;
            float p = __expf(fmaf(s[r], scale, -m4[r >> 2][r & 3]));
            int chs = (kh * 4 + (l31 >> 3)) ^ (row & 7);
            Ps[row * 64 + chs * 8 + (l31 & 7)] = (F16)p;
        }
        __syncthreads();                       // P visible to all waves

        // PV: wave's 64-v slice over all 64 q; contraction 64 keys (4 chunks)
#pragma unroll
        for (int kc = 0; kc < 4; kc++) {
            f16x8 pa0 = *(f16x8*)&Ps[(l31) * 64 + (((kc * 2 + lh) ^ x7) * 8)];
            f16x8 pa1 = *(f16x8*)&Ps[(32 + l31) * 64 + (((kc * 2 + lh) ^ x7) * 8)];
            if (kh == 0)                        // waves 0,2 accumulate row sums
                lsum = __builtin_amdgcn_mfma_f32_32x32x16_f16(qg == 0 ? pa0 : pa1,
                                                              one8, lsum, 0, 0, 0);
#pragma unroll
            for (int vh = 0; vh < 2; vh++) {
                int vrow = w * 64 + vh * 32 + l31;
                f16x8 vb = *(f16x8*)&Vl[vrow * 64 + (((kc * 2 + lh) ^ x7) * 8)];
                acc[0][vh] = __builtin_amdgcn_mfma_f32_32x32x16_f16(pa0, vb, acc[0][vh], 0, 0, 0);
                acc[1][vh] = __builtin_amdgcn_mfma_f32_32x32x16_f16(pa1, vb, acc[1][vh], 0, 0, 0);
            }
        }
    }

    // epilogue: broadcast lsum, write normalized partial + L = m + ln(l)
    __syncthreads();
    if (kh == 0 && l31 == 0) {
#pragma unroll
        for (int r = 0; r < 16; r++)
            crl[qg * 32 + (r & 3) + 8 * (r >> 2) + 4 * lh] = lsum[r];
    }
    __syncthreads();

    F16* cb = parts + (size_t)kset * PSET + (size_t)b * NN * KCH;
#pragma unroll
    for (int qg2 = 0; qg2 < 2; qg2++) {
        f32x4 iv[4];
#pragma unroll
        for (int g = 0; g < 4; g++) {
            f32x4 lv = *(f32x4*)&crl[qg2 * 32 + g * 8 + lh * 4];
#pragma unroll
            for (int j = 0; j < 4; j++) iv[g][j] = 1.0f / lv[j];
        }
#pragma unroll
        for (int vh = 0; vh < 2; vh++) {
#pragma unroll
            for (int r = 0; r < 16; r++) {
                int n = n0 + qg2 * 32 + (r & 3) + 8 * (r >> 2) + 4 * lh;
                cb[(size_t)n * KCH + w * 64 + vh * 32 + l31] =
                    (F16)(acc[qg2][vh][r] * iv[r >> 2][r & 3]);
            }
        }
    }
    float* Lb = Lbuf + ((size_t)kset * NB + b) * NN;
    if (kh == 0 && l31 == 0) {
#pragma unroll
        for (int r = 0; r < 16; r++) {
            int n = n0 + qg * 32 + (r & 3) + 8 * (r >> 2) + 4 * lh;
            Lb[n] = m4[r >> 2][r & 3] + __logf(lsum[r]);
        }
    }
}

// ---------------------------------------------------------------- out GEMM (fused split-K merge)
__global__ __launch_bounds__(256) void k_out_gemm(const F16* __restrict__ parts,
                                                  const float* __restrict__ Lbuf,
                                                  const float* __restrict__ w_w,
                                                  const float* __restrict__ w_b,
                                                  float* __restrict__ out) {
    __shared__ F16 Al[128][40];
    __shared__ F16 Bl[128][40];
    __shared__ float lw0[128], lw1[128];
    int b = blockIdx.z;
    int m0 = blockIdx.y * 128;
    int n0 = blockIdx.x * 128;
    int t = threadIdx.x, w = t >> 6, l = t & 63;
    int wr = w >> 1, wc = w & 1;
    int lr = l >> 4, lc = l & 15;

    if (t < 128) {
        int n = n0 + t;
        float L0 = Lbuf[(size_t)b * NN + n];
        float L1 = Lbuf[(size_t)NBNN + (size_t)b * NN + n];
        float M = fmaxf(L0, L1);
        float e0 = __expf(L0 - M), e1 = __expf(L1 - M);
        float inv = 1.0f / (e0 + e1);
        lw0[t] = e0 * inv; lw1[t] = e1 * inv;
    }
    __syncthreads();
    int row0 = t >> 2, row1 = (t >> 2) + 64;
    float w00 = lw0[row0], w10 = lw1[row0];
    float w01 = lw0[row1], w11 = lw1[row1];

    f32x4 acc[4][4];
    const f32x4 fz = {0.f, 0.f, 0.f, 0.f};
#pragma unroll
    for (int i = 0; i < 4; i++)
#pragma unroll
        for (int j = 0; j < 4; j++) acc[i][j] = fz;

    for (int kt = 0; kt < KCH / 32; kt++) {
        int c0 = kt * 32;
        __syncthreads();
#pragma unroll
        for (int p = 0; p < 4; p++) {
            int row = (t >> 3) + p * 32;
            int cc = (t & 7) * 4;
            float4 v = *(const float4*)&w_w[(size_t)(m0 + row) * KCH + c0 + cc];
            f16x4 h; h[0] = (F16)v.x; h[1] = (F16)v.y; h[2] = (F16)v.z; h[3] = (F16)v.w;
            *(f16x4*)&Al[row][cc] = h;
        }
#pragma unroll
        for (int p = 0; p < 2; p++) {
            int row = (p == 0) ? row0 : row1;
            float wa = (p == 0) ? w00 : w01;
            float wb2 = (p == 0) ? w10 : w11;
            int cc = (t & 3) * 8;
            size_t base = ((size_t)b * NN + n0 + row) * KCH + c0 + cc;
            f16x8 p0 = *(const f16x8*)&parts[base];
            f16x8 p1 = *(const f16x8*)&parts[PSET + base];
            f16x8 m;
#pragma unroll
            for (int j = 0; j < 8; j++)
                m[j] = (F16)(wa * (float)p0[j] + wb2 * (float)p1[j]);
            *(f16x8*)&Bl[row][cc] = m;
        }
        __syncthreads();
        f16x8 a[4];
#pragma unroll
        for (int fi = 0; fi < 4; fi++)
            a[fi] = *(f16x8*)&Al[wr * 64 + fi * 16 + lc][lr * 8];
#pragma unroll
        for (int fj = 0; fj < 4; fj++) {
            f16x8 bb = *(f16x8*)&Bl[wc * 64 + fj * 16 + lc][lr * 8];
#pragma unroll
            for (int fi = 0; fi < 4; fi++)
                acc[fi][fj] = __builtin_amdgcn_mfma_f32_16x16x32_f16(a[fi], bb, acc[fi][fj], 0, 0, 0);
        }
    }

#pragma unroll
    for (int fi = 0; fi < 4; fi++) {
        int o0 = m0 + wr * 64 + fi * 16 + lr * 4;
#pragma unroll
        for (int fj = 0; fj < 4; fj++) {
            int n = n0 + wc * 64 + fj * 16 + lc;
#pragma unroll
            for (int r = 0; r < 4; r++) {
                out[((size_t)b * OCH + o0 + r) * NN + n] = acc[fi][fj][r] + w_b[o0 + r];
            }
        }
    }
}

// ---------------------------------------------------------------- launch
extern "C" void kernel_launch(void* const* d_in, const int* in_sizes, int n_in,
                              void* d_out, int out_size, void* d_ws, size_t ws_size,
                              hipStream_t stream) {
    const float* x       = (const float*)d_in[0];
    const float* key_w   = (const float*)d_in[1];
    const float* key_b   = (const float*)d_in[2];
    const float* gamma   = (const float*)d_in[3];
    const float* beta    = (const float*)d_in[4];
    const float* mean    = (const float*)d_in[5];
    const float* var     = (const float*)d_in[6];
    const float* value_w = (const float*)d_in[7];
    const float* value_b = (const float*)d_in[8];
    const float* w_w     = (const float*)d_in[9];
    const float* w_b     = (const float*)d_in[10];
    float* out = (float*)d_out;
    char* ws = (char*)d_ws;

    // layout: parts 2*8.39M (overlays dead xT) | KQt 8.39M | Vg 8.39M |
    // L 128K | Mrow 64K | Mb 16B   (total ~50.53 MB; ws >= 50.59 MB proven R4)
    size_t kqt_off  = 2 * PSET * 2;
    size_t vg_off   = kqt_off + 8388608ull;
    size_t l_off    = vg_off + 8388608ull;
    size_t mrow_off = l_off + (size_t)2 * NBNN * 4;
    size_t mb_off   = mrow_off + (size_t)NBNN * 4;

    F16*   xT    = (F16*)(ws);
    F16*   parts = (F16*)(ws);
    F16*   KQt   = (F16*)(ws + kqt_off);
    F16*   Vg    = (F16*)(ws + vg_off);
    float* Lbuf  = (float*)(ws + l_off);
    float* Mrow  = (float*)(ws + mrow_off);
    float* Mb    = (float*)(ws + mb_off);

    hipMemsetAsync(Mb, 0, NB * sizeof(float), stream);
    hipLaunchKernelGGL(k_transpose, dim3(8, 64, 4), dim3(256), 0, stream, x, xT);
    hipLaunchKernelGGL(k_kv_gemm, dim3(32, 4, 4), dim3(256), 0, stream,
                       xT, key_w, key_b, gamma, beta, mean, var, value_w, value_b, KQt, Vg);
    hipLaunchKernelGGL(k_rowmax, dim3(256), dim3(256), 0, stream, KQt, Mrow, Mb);
    hipLaunchKernelGGL(k_flash, dim3(512), dim3(256), 0, stream,
                       KQt, Vg, Mrow, Mb, parts, Lbuf);
    hipLaunchKernelGGL(k_out_gemm, dim3(32, 4, 4), dim3(256), 0, stream,
                       parts, Lbuf, w_w, w_b, out);
}